// Round 1
// baseline (129.995 us; speedup 1.0000x reference)
//
#include <hip/hip_runtime.h>
#include <hip/hip_bf16.h>
#include <float.h>

#define N_ROWS 8192
#define D_COLS 4096

// Kernel 1: Err[row] = sum_j (in[row][j] - tg[row][j])^2
__global__ __launch_bounds__(256) void row_sqerr_kernel(
    const float* __restrict__ in, const float* __restrict__ tg,
    float* __restrict__ err) {
  const int row = blockIdx.x;
  const int t = threadIdx.x;
  const float4* a = (const float4*)(in + (size_t)row * D_COLS);
  const float4* b = (const float4*)(tg + (size_t)row * D_COLS);
  float acc = 0.f;
#pragma unroll
  for (int k = 0; k < 4; ++k) {
    float4 x = a[t + k * 256];
    float4 y = b[t + k * 256];
    float d0 = x.x - y.x, d1 = x.y - y.y, d2 = x.z - y.z, d3 = x.w - y.w;
    acc += d0 * d0 + d1 * d1 + d2 * d2 + d3 * d3;
  }
  // wave-64 shuffle reduce
#pragma unroll
  for (int off = 32; off > 0; off >>= 1) acc += __shfl_down(acc, off);
  __shared__ float wsum[4];
  const int lane = t & 63, wid = t >> 6;
  if (lane == 0) wsum[wid] = acc;
  __syncthreads();
  if (t == 0) err[row] = wsum[0] + wsum[1] + wsum[2] + wsum[3];
}

// Kernel 2: sort Err, scan, find optimal split (Otsu-like), emit scalar loss.
// Single block, 1024 threads, 8 elements/thread.
__global__ __launch_bounds__(1024) void select_kernel(
    const float* __restrict__ err, float* __restrict__ out) {
  __shared__ float s[N_ROWS];        // 32 KB sorted errors
  __shared__ double dsum[1024];      // 8 KB scan of sums -> reused for obj
  __shared__ double dsq[1024];       // 8 KB scan of sumsq -> reused for c1@best
  __shared__ int sidx[1024];         // 4 KB argmin indices

  const int t = threadIdx.x;

  // load (coalesced)
#pragma unroll
  for (int m = 0; m < 8; ++m) s[(m << 10) | t] = err[(m << 10) | t];
  __syncthreads();

  // bitonic sort, ascending
  for (int k = 2; k <= N_ROWS; k <<= 1) {
    for (int j = k >> 1; j > 0; j >>= 1) {
      __syncthreads();
#pragma unroll
      for (int m = 0; m < 8; ++m) {
        int i = (m << 10) | t;
        int ixj = i ^ j;
        if (ixj > i) {
          float a = s[i], b = s[ixj];
          bool up = ((i & k) == 0);
          if ((a > b) == up) { s[i] = b; s[ixj] = a; }
        }
      }
    }
  }
  __syncthreads();

  // per-thread local sums over its 8 consecutive sorted elements
  float vals[8];
  double lsum = 0.0, lsq = 0.0;
#pragma unroll
  for (int k = 0; k < 8; ++k) {
    float v = s[t * 8 + k];
    vals[k] = v;
    lsum += (double)v;
    lsq += (double)v * (double)v;
  }
  dsum[t] = lsum;
  dsq[t] = lsq;
  __syncthreads();

  // Hillis-Steele inclusive scan over 1024 thread-totals (double)
  for (int off = 1; off < 1024; off <<= 1) {
    double a = (t >= off) ? dsum[t - off] : 0.0;
    double b = (t >= off) ? dsq[t - off] : 0.0;
    __syncthreads();
    dsum[t] += a;
    dsq[t] += b;
    __syncthreads();
  }

  const double total = dsum[1023];
  const double total_sq = dsq[1023];
  double c1 = dsum[t] - lsum;  // exclusive prefix
  double q1 = dsq[t] - lsq;
  __syncthreads();  // done reading scan results; LDS will be reused

  const double nf = (double)N_ROWS;
  const double all_mean = total / nf;
  const double Sb = total_sq - nf * all_mean * all_mean;

  double best = DBL_MAX;
  int bidx = N_ROWS;  // sentinel larger than any valid index
  double bc1 = 0.0;
#pragma unroll
  for (int k = 0; k < 8; ++k) {
    int i = t * 8 + k;
    double v = (double)vals[k];
    c1 += v;
    q1 += v * v;
    if (i <= N_ROWS - 2) {  // split indices 0..N-2 (n1 = 1..N-1)
      double n1 = (double)(i + 1);
      double n2 = nf - n1;
      double mean1 = c1 / n1;
      double mean2 = (total - c1) / n2;
      double Sw1 = q1 - n1 * mean1 * mean1;
      double Sw2 = (total_sq - q1) - n2 * mean2 * mean2;
      double obj = (Sw1 + Sw2) / Sb;
      if (obj < best) { best = obj; bidx = i; bc1 = c1; }
    }
  }

  // argmin tree-reduce (first-index tie-break)
  dsum[t] = best;
  dsq[t] = bc1;
  sidx[t] = bidx;
  for (int off = 512; off > 0; off >>= 1) {
    __syncthreads();
    if (t < off) {
      double o2 = dsum[t + off];
      int i2 = sidx[t + off];
      if (o2 < dsum[t] || (o2 == dsum[t] && i2 < sidx[t])) {
        dsum[t] = o2;
        sidx[t] = i2;
        dsq[t] = dsq[t + off];
      }
    }
  }
  __syncthreads();
  if (t == 0) {
    double opt_obj = dsum[0];
    int i_opt = sidx[0];
    double inlier_sum = dsq[0];
    double T = (double)(i_opt + 1);
    out[0] = (float)(inlier_sum / T + 0.1 * opt_obj);
  }
}

extern "C" void kernel_launch(void* const* d_in, const int* in_sizes, int n_in,
                              void* d_out, int out_size, void* d_ws, size_t ws_size,
                              hipStream_t stream) {
  const float* input = (const float*)d_in[0];
  const float* target = (const float*)d_in[1];
  float* out = (float*)d_out;
  float* err = (float*)d_ws;  // 8192 floats = 32 KB scratch

  row_sqerr_kernel<<<N_ROWS, 256, 0, stream>>>(input, target, err);
  select_kernel<<<1, 1024, 0, stream>>>(err, out);
}

// Round 2
// 129.692 us; speedup vs baseline: 1.0023x; 1.0023x over previous
//
#include <hip/hip_runtime.h>
#include <hip/hip_bf16.h>
#include <float.h>

#define N_ROWS 8192
#define D_COLS 4096

// Kernel 1: Err[row] = sum_j (in[row][j] - tg[row][j])^2
// One wave (64 lanes) per row. 4096 floats / 64 lanes = 16 float4 per lane,
// loaded in two explicit batches of 8 pairs so 16 dwordx4 loads are in
// flight before any FMA (defeats the compiler's register-minimizing
// serialization seen in R1: VGPR=20, VALUBusy=4%, BW=17%).
__global__ __launch_bounds__(256) void row_sqerr_kernel(
    const float* __restrict__ in, const float* __restrict__ tg,
    float* __restrict__ err) {
  const int row = (blockIdx.x << 2) | (threadIdx.x >> 6);
  const int lane = threadIdx.x & 63;
  const float4* a = (const float4*)(in + (size_t)row * D_COLS) + lane;
  const float4* b = (const float4*)(tg + (size_t)row * D_COLS) + lane;

  float acc0 = 0.f, acc1 = 0.f, acc2 = 0.f, acc3 = 0.f;
  float4 xa[8], xb[8];

#pragma unroll
  for (int s = 0; s < 2; ++s) {
    // issue 16 independent loads
#pragma unroll
    for (int p = 0; p < 8; ++p) xa[p] = a[(s * 8 + p) * 64];
#pragma unroll
    for (int p = 0; p < 8; ++p) xb[p] = b[(s * 8 + p) * 64];
    // consume
#pragma unroll
    for (int p = 0; p < 8; ++p) {
      float d0 = xa[p].x - xb[p].x;
      float d1 = xa[p].y - xb[p].y;
      float d2 = xa[p].z - xb[p].z;
      float d3 = xa[p].w - xb[p].w;
      acc0 += d0 * d0;
      acc1 += d1 * d1;
      acc2 += d2 * d2;
      acc3 += d3 * d3;
    }
  }
  float acc = (acc0 + acc1) + (acc2 + acc3);
#pragma unroll
  for (int off = 32; off > 0; off >>= 1) acc += __shfl_down(acc, off);
  if (lane == 0) err[row] = acc;
}

// Kernel 2: sort Err, scan, find optimal split (Otsu-like), emit scalar loss.
// Single block, 1024 threads, 8 elements/thread.
__global__ __launch_bounds__(1024) void select_kernel(
    const float* __restrict__ err, float* __restrict__ out) {
  __shared__ float s[N_ROWS];        // 32 KB sorted errors
  __shared__ double dsum[1024];      // 8 KB scan of sums -> reused for obj
  __shared__ double dsq[1024];       // 8 KB scan of sumsq -> reused for c1@best
  __shared__ int sidx[1024];         // 4 KB argmin indices

  const int t = threadIdx.x;

  // load (coalesced)
#pragma unroll
  for (int m = 0; m < 8; ++m) s[(m << 10) | t] = err[(m << 10) | t];
  __syncthreads();

  // bitonic sort, ascending
  for (int k = 2; k <= N_ROWS; k <<= 1) {
    for (int j = k >> 1; j > 0; j >>= 1) {
      __syncthreads();
#pragma unroll
      for (int m = 0; m < 8; ++m) {
        int i = (m << 10) | t;
        int ixj = i ^ j;
        if (ixj > i) {
          float a = s[i], b = s[ixj];
          bool up = ((i & k) == 0);
          if ((a > b) == up) { s[i] = b; s[ixj] = a; }
        }
      }
    }
  }
  __syncthreads();

  // per-thread local sums over its 8 consecutive sorted elements
  float vals[8];
  double lsum = 0.0, lsq = 0.0;
#pragma unroll
  for (int k = 0; k < 8; ++k) {
    float v = s[t * 8 + k];
    vals[k] = v;
    lsum += (double)v;
    lsq += (double)v * (double)v;
  }
  dsum[t] = lsum;
  dsq[t] = lsq;
  __syncthreads();

  // Hillis-Steele inclusive scan over 1024 thread-totals (double)
  for (int off = 1; off < 1024; off <<= 1) {
    double a = (t >= off) ? dsum[t - off] : 0.0;
    double b = (t >= off) ? dsq[t - off] : 0.0;
    __syncthreads();
    dsum[t] += a;
    dsq[t] += b;
    __syncthreads();
  }

  const double total = dsum[1023];
  const double total_sq = dsq[1023];
  double c1 = dsum[t] - lsum;  // exclusive prefix
  double q1 = dsq[t] - lsq;
  __syncthreads();  // done reading scan results; LDS will be reused

  const double nf = (double)N_ROWS;
  const double all_mean = total / nf;
  const double Sb = total_sq - nf * all_mean * all_mean;

  double best = DBL_MAX;
  int bidx = N_ROWS;  // sentinel larger than any valid index
  double bc1 = 0.0;
#pragma unroll
  for (int k = 0; k < 8; ++k) {
    int i = t * 8 + k;
    double v = (double)vals[k];
    c1 += v;
    q1 += v * v;
    if (i <= N_ROWS - 2) {  // split indices 0..N-2 (n1 = 1..N-1)
      double n1 = (double)(i + 1);
      double n2 = nf - n1;
      double mean1 = c1 / n1;
      double mean2 = (total - c1) / n2;
      double Sw1 = q1 - n1 * mean1 * mean1;
      double Sw2 = (total_sq - q1) - n2 * mean2 * mean2;
      double obj = (Sw1 + Sw2) / Sb;
      if (obj < best) { best = obj; bidx = i; bc1 = c1; }
    }
  }

  // argmin tree-reduce (first-index tie-break)
  dsum[t] = best;
  dsq[t] = bc1;
  sidx[t] = bidx;
  for (int off = 512; off > 0; off >>= 1) {
    __syncthreads();
    if (t < off) {
      double o2 = dsum[t + off];
      int i2 = sidx[t + off];
      if (o2 < dsum[t] || (o2 == dsum[t] && i2 < sidx[t])) {
        dsum[t] = o2;
        sidx[t] = i2;
        dsq[t] = dsq[t + off];
      }
    }
  }
  __syncthreads();
  if (t == 0) {
    double opt_obj = dsum[0];
    int i_opt = sidx[0];
    double inlier_sum = dsq[0];
    double T = (double)(i_opt + 1);
    out[0] = (float)(inlier_sum / T + 0.1 * opt_obj);
  }
}

extern "C" void kernel_launch(void* const* d_in, const int* in_sizes, int n_in,
                              void* d_out, int out_size, void* d_ws, size_t ws_size,
                              hipStream_t stream) {
  const float* input = (const float*)d_in[0];
  const float* target = (const float*)d_in[1];
  float* out = (float*)d_out;
  float* err = (float*)d_ws;  // 8192 floats = 32 KB scratch

  row_sqerr_kernel<<<N_ROWS / 4, 256, 0, stream>>>(input, target, err);
  select_kernel<<<1, 1024, 0, stream>>>(err, out);
}